// Round 1
// baseline (153.859 us; speedup 1.0000x reference)
//
#include <hip/hip_runtime.h>

// ---------------------------------------------------------------------------
// GraphAttn: out = relu( (mergeheads( tanh((QK^T/4) * adj) @ V )) @ wo )
// B=32, N=512, F_IN=64, H=8, D=16, OUT=128.
// Three kernels: qkv proj (MFMA), fused attention (MFMA + tanh), out proj.
// All heavy math in bf16 MFMA with f32 accumulation (threshold 0.1356 allows).
// ---------------------------------------------------------------------------

typedef __bf16 bf16x8 __attribute__((ext_vector_type(8)));
typedef __bf16 bf16x4 __attribute__((ext_vector_type(4)));
typedef float  f32x4  __attribute__((ext_vector_type(4)));

#define B_    32
#define N_    512
#define FIN_  64
#define H_    8
#define D_    16
#define OD_   128
#define BH_   (B_ * H_)   // 256

// ---------------------------------------------------------------------------
// Kernel 1: Q,K,V = x @ {wq,wk,wv}.  x:[B*N,64] f32, w:[64,128] f32.
// Outputs bf16: Qb,Kb = [bh][n][16] row-major;  VT = [bh][16][n] (transposed).
// 256 blocks x 256 thr (4 waves); each block = 64 rows; wave = 16-row strip.
// W^T (all 3 concatenated, 384 cols x 64 k) staged in LDS, padded rows.
// ---------------------------------------------------------------------------
__global__ __launch_bounds__(256) void qkv_kernel(
    const float* __restrict__ x,  const float* __restrict__ wq,
    const float* __restrict__ wk, const float* __restrict__ wv,
    __bf16* __restrict__ Qb, __bf16* __restrict__ Kb, __bf16* __restrict__ VT)
{
    __shared__ __align__(16) __bf16 WT[384 * 72];   // [j][k], rows padded 64->72

    const int tid = threadIdx.x;
    for (int idx = tid; idx < 384 * 64; idx += 256) {
        int j = idx % 384;              // global output col (q|k|v)
        int k = idx / 384;
        const float* w = (j < 128) ? wq : ((j < 256) ? wk : wv);
        int jj = j & 127;
        WT[j * 72 + k] = (__bf16)w[k * 128 + jj];
    }
    __syncthreads();

    const int lane = tid & 63;
    const int wv_id = tid >> 6;       // wave 0..3
    const int g    = lane >> 4;       // lane group 0..3
    const int lr   = lane & 15;

    const int rowA = blockIdx.x * 64 + wv_id * 16 + lr;  // A-frag row
    // A-frags: lane holds x[rowA, kk*32 + g*8 .. +8) as bf16
    bf16x8 afrag[2];
#pragma unroll
    for (int kk = 0; kk < 2; ++kk) {
        const float* xp = x + rowA * 64 + kk * 32 + g * 8;
        f32x4 x0 = *(const f32x4*)(xp);
        f32x4 x1 = *(const f32x4*)(xp + 4);
        bf16x8 a;
#pragma unroll
        for (int e = 0; e < 4; ++e) { a[e] = (__bf16)x0[e]; a[4 + e] = (__bf16)x1[e]; }
        afrag[kk] = a;
    }

    const int b    = (blockIdx.x * 64) >> 9;            // batch (64 | 512)
    const int nn0  = (blockIdx.x * 64 + wv_id * 16 + g * 4) & 511; // out row base

#pragma unroll 1
    for (int j0 = 0; j0 < 384; j0 += 16) {
        f32x4 acc = {0.f, 0.f, 0.f, 0.f};
#pragma unroll
        for (int kk = 0; kk < 2; ++kk) {
            bf16x8 bfrag = *(const bf16x8*)&WT[(j0 + lr) * 72 + kk * 32 + g * 8];
            acc = __builtin_amdgcn_mfma_f32_16x16x32_bf16(afrag[kk], bfrag, acc, 0, 0, 0);
        }
        const int t  = j0 >> 7;          // 0=q 1=k 2=v
        const int jj = (j0 + lr) & 127;  // col within the 128-wide output
        const int h  = jj >> 4;
        const int d  = jj & 15;
        const int bh = b * 8 + h;
        if (t == 2) {
            bf16x4 pk;
#pragma unroll
            for (int r = 0; r < 4; ++r) pk[r] = (__bf16)acc[r];
            *(bf16x4*)&VT[(bh * 16 + d) * 512 + nn0] = pk;   // 4 consecutive n
        } else {
            __bf16* dst = (t == 0) ? Qb : Kb;
#pragma unroll
            for (int r = 0; r < 4; ++r)
                dst[(bh * 512 + (nn0 + r)) * 16 + d] = (__bf16)acc[r];
        }
    }
}

// ---------------------------------------------------------------------------
// Kernel 2: fused attention.  Per block: (b, 16-row n-strip), 8 waves = 8 heads.
// Per 32-m tile: S^T = mfma(K,Q) (zero-padded d 16->32), tanh(S*adj/4),
// bf16 pack -> per-wave LDS P[16][40] (padded, 2-way max), re-read as PV A-frag,
// accumulate h with mfma(P, V^T-frag).  No barriers (waves independent).
// ---------------------------------------------------------------------------
__device__ __forceinline__ float tanh_q(float sadj) {
    // tanh(sadj * 0.25) = 1 - 2 / (exp2(sadj * 0.5*log2(e)) + 1)
    const float C = 0.7213475204444817f;   // 0.25 * 2 * log2(e)
    float e = __builtin_amdgcn_exp2f(sadj * C);
    float r = __builtin_amdgcn_rcpf(e + 1.0f);
    return 1.0f - 2.0f * r;
}

__global__ __launch_bounds__(512) void attn_kernel(
    const float* __restrict__ adj,
    const __bf16* __restrict__ Qb, const __bf16* __restrict__ Kb,
    const __bf16* __restrict__ VT, __bf16* __restrict__ Hb)
{
    __shared__ __align__(16) __bf16 P[8][16][40];   // per-wave, rows padded 32->40

    const int tid  = threadIdx.x;
    const int lane = tid & 63;
    const int h    = tid >> 6;        // wave = head
    const int g    = lane >> 4;
    const int lr   = lane & 15;
    const int b    = blockIdx.y;
    const int n0   = blockIdx.x * 16;
    const int bh   = b * 8 + h;

    // Q as MFMA B-operand: lane holds Q[n0+lr][g*8..+8) for g<2, zeros else.
    bf16x8 qf = {};
    if (g < 2) qf = *(const bf16x8*)&Qb[(bh * 512 + n0 + lr) * 16 + g * 8];

    const float* adj_row = adj + ((long)b * 512 + n0 + lr) * 512;  // row n=n0+lr

    f32x4 accH = {0.f, 0.f, 0.f, 0.f};

    for (int m0 = 0; m0 < 512; m0 += 32) {
        bf16x8 kf0 = {}, kf1 = {};
        if (g < 2) {
            kf0 = *(const bf16x8*)&Kb[(bh * 512 + m0 +      lr) * 16 + g * 8];
            kf1 = *(const bf16x8*)&Kb[(bh * 512 + m0 + 16 + lr) * 16 + g * 8];
        }
        bf16x8 vf = *(const bf16x8*)&VT[(bh * 16 + lr) * 512 + m0 + g * 8];
        f32x4 a0 = *(const f32x4*)(adj_row + m0 +      g * 4);
        f32x4 a1 = *(const f32x4*)(adj_row + m0 + 16 + g * 4);

        const f32x4 z = {0.f, 0.f, 0.f, 0.f};
        // S^T tiles: lane holds S[n = n0+lr][m = m0 + t*16 + g*4 + r]
        f32x4 s0 = __builtin_amdgcn_mfma_f32_16x16x32_bf16(kf0, qf, z, 0, 0, 0);
        f32x4 s1 = __builtin_amdgcn_mfma_f32_16x16x32_bf16(kf1, qf, z, 0, 0, 0);

        bf16x4 p0, p1;
#pragma unroll
        for (int r = 0; r < 4; ++r) {
            p0[r] = (__bf16)tanh_q(s0[r] * a0[r]);
            p1[r] = (__bf16)tanh_q(s1[r] * a1[r]);
        }
        // P[n][m_local]: wave-local round-trip to re-fragment for PV A-operand
        *(bf16x4*)&P[h][lr][g * 4]      = p0;
        *(bf16x4*)&P[h][lr][16 + g * 4] = p1;
        bf16x8 af = *(const bf16x8*)&P[h][lr][g * 8];   // attn[n=lr][m=g*8..+8)

        accH = __builtin_amdgcn_mfma_f32_16x16x32_bf16(af, vf, accH, 0, 0, 0);
    }

    // h tile: lane holds h[n = n0 + g*4 + r][d = lr]; write Hb[b*512+n][h*16+d]
#pragma unroll
    for (int r = 0; r < 4; ++r)
        Hb[((long)b * 512 + n0 + g * 4 + r) * 128 + h * 16 + lr] = (__bf16)accH[r];
}

// ---------------------------------------------------------------------------
// Kernel 3: out = relu(Hb @ wo).  Hb:[16384,128] bf16, wo:[128,128] f32.
// 256 blocks x 256 thr; wo^T staged in LDS (padded).
// ---------------------------------------------------------------------------
__global__ __launch_bounds__(256) void oproj_kernel(
    const __bf16* __restrict__ Hb, const float* __restrict__ wo,
    float* __restrict__ out)
{
    __shared__ __align__(16) __bf16 WoT[128 * 136];   // [j][k], rows padded 128->136

    const int tid = threadIdx.x;
    for (int idx = tid; idx < 128 * 128; idx += 256) {
        int j = idx & 127;
        int k = idx >> 7;
        WoT[j * 136 + k] = (__bf16)wo[k * 128 + j];
    }
    __syncthreads();

    const int lane = tid & 63;
    const int wv_id = tid >> 6;
    const int g    = lane >> 4;
    const int lr   = lane & 15;

    const int rowA = blockIdx.x * 64 + wv_id * 16 + lr;
    bf16x8 afrag[4];
#pragma unroll
    for (int kk = 0; kk < 4; ++kk)
        afrag[kk] = *(const bf16x8*)&Hb[(long)rowA * 128 + kk * 32 + g * 8];

    const int orow = blockIdx.x * 64 + wv_id * 16 + g * 4;
#pragma unroll 1
    for (int j0 = 0; j0 < 128; j0 += 16) {
        f32x4 acc = {0.f, 0.f, 0.f, 0.f};
#pragma unroll
        for (int kk = 0; kk < 4; ++kk) {
            bf16x8 bfrag = *(const bf16x8*)&WoT[(j0 + lr) * 136 + kk * 32 + g * 8];
            acc = __builtin_amdgcn_mfma_f32_16x16x32_bf16(afrag[kk], bfrag, acc, 0, 0, 0);
        }
#pragma unroll
        for (int r = 0; r < 4; ++r)
            out[(long)(orow + r) * 128 + j0 + lr] = fmaxf(acc[r], 0.0f);
    }
}

// ---------------------------------------------------------------------------
extern "C" void kernel_launch(void* const* d_in, const int* in_sizes, int n_in,
                              void* d_out, int out_size, void* d_ws, size_t ws_size,
                              hipStream_t stream) {
    const float* x   = (const float*)d_in[0];
    const float* adj = (const float*)d_in[1];
    const float* wq  = (const float*)d_in[2];
    const float* wk  = (const float*)d_in[3];
    const float* wv  = (const float*)d_in[4];
    const float* wo  = (const float*)d_in[5];
    float* out = (float*)d_out;

    __bf16* Qb = (__bf16*)d_ws;                  // 256*512*16 bf16 = 4 MiB
    __bf16* Kb = Qb + BH_ * N_ * D_;
    __bf16* VT = Kb + BH_ * N_ * D_;             // [bh][16][512]
    __bf16* Hb = VT + BH_ * N_ * D_;             // [B*N][128]

    qkv_kernel<<<256, 256, 0, stream>>>(x, wq, wk, wv, Qb, Kb, VT);
    attn_kernel<<<dim3(32, 32), 512, 0, stream>>>(adj, Qb, Kb, VT, Hb);
    oproj_kernel<<<256, 256, 0, stream>>>(Hb, wo, out);
}

// Round 5
// 143.088 us; speedup vs baseline: 1.0753x; 1.0753x over previous
//
#include <hip/hip_runtime.h>

// ---------------------------------------------------------------------------
// GraphAttn: out = relu( (mergeheads( tanh((QK^T/4) * adj) @ V )) @ wo )
// B=32, N=512, F_IN=64, H=8, D=16, OUT=128.
// v2: prep (bf16 W^T) -> qkv (LDS-free MFMA) -> attn (permuted-K PV, no P-LDS,
//     adj staged in swizzled LDS) -> oproj (LDS-free MFMA).
// ---------------------------------------------------------------------------

typedef __bf16 bf16x8 __attribute__((ext_vector_type(8)));
typedef __bf16 bf16x4 __attribute__((ext_vector_type(4)));
typedef float  f32x4  __attribute__((ext_vector_type(4)));

#define MFMA16(a, b, c) __builtin_amdgcn_mfma_f32_16x16x32_bf16((a), (b), (c), 0, 0, 0)

// ---------------------------------------------------------------------------
// prep: WTb[j][k] = w{q,k,v}[k][j&127] (384x64), WoTb[j][k] = wo[k][j] (128x128)
// Coalesced f32x4 reads, scattered bf16 writes (tiny, L2).
// ---------------------------------------------------------------------------
__global__ __launch_bounds__(256) void prep_kernel(
    const float* __restrict__ wq, const float* __restrict__ wk,
    const float* __restrict__ wv, const float* __restrict__ wo,
    __bf16* __restrict__ WTb, __bf16* __restrict__ WoTb)
{
    int idx = blockIdx.x * 256 + threadIdx.x;
    if (idx < 6144) {                       // 96 j-groups x 64 k
        int j4 = idx % 96, k = idx / 96, j = j4 * 4;
        const float* w = (j < 128) ? wq : ((j < 256) ? wk : wv);
        f32x4 v = *(const f32x4*)&w[k * 128 + (j & 127)];
#pragma unroll
        for (int e = 0; e < 4; ++e) WTb[(j + e) * 64 + k] = (__bf16)v[e];
    } else if (idx < 6144 + 4096) {         // 32 j-groups x 128 k
        int i2 = idx - 6144;
        int j4 = i2 % 32, k = i2 / 32, j = j4 * 4;
        f32x4 v = *(const f32x4*)&wo[k * 128 + j];
#pragma unroll
        for (int e = 0; e < 4; ++e) WoTb[(j + e) * 128 + k] = (__bf16)v[e];
    }
}

// ---------------------------------------------------------------------------
// qkv: Q,K = [bh][n][16] row-major bf16; VT = [bh][16][n].
// 1024 blocks x 256 thr; block = 16 rows; wave w handles 6 of 24 j-tiles.
// B-frags read directly from global WTb (L1-hot, 48 KB).
// ---------------------------------------------------------------------------
__global__ __launch_bounds__(256) void qkv_kernel(
    const float* __restrict__ x, const __bf16* __restrict__ WTb,
    __bf16* __restrict__ Qb, __bf16* __restrict__ Kb, __bf16* __restrict__ VT)
{
    const int tid = threadIdx.x, lane = tid & 63, w = tid >> 6;
    const int g = lane >> 4, lr = lane & 15;
    const long R0 = (long)blockIdx.x * 16;
    const int b = (int)(R0 >> 9);
    const int nloc = (int)(R0 & 511) + g * 4;

    bf16x8 af[2];
#pragma unroll
    for (int kk = 0; kk < 2; ++kk) {
        const float* xp = x + (R0 + lr) * 64 + kk * 32 + g * 8;
        f32x4 x0 = *(const f32x4*)xp, x1 = *(const f32x4*)(xp + 4);
        bf16x8 a;
#pragma unroll
        for (int e = 0; e < 4; ++e) { a[e] = (__bf16)x0[e]; a[4 + e] = (__bf16)x1[e]; }
        af[kk] = a;
    }

#pragma unroll 2
    for (int i = 0; i < 6; ++i) {
        const int j0 = (w * 6 + i) * 16;
        f32x4 acc = {0.f, 0.f, 0.f, 0.f};
#pragma unroll
        for (int kk = 0; kk < 2; ++kk) {
            bf16x8 bf = *(const bf16x8*)&WTb[(j0 + lr) * 64 + kk * 32 + g * 8];
            acc = MFMA16(af[kk], bf, acc);
        }
        const int jj = (j0 + lr) & 127, hh = jj >> 4, d = jj & 15;
        const int bh = b * 8 + hh, t = j0 >> 7;
        if (t == 2) {
            bf16x4 pk;
#pragma unroll
            for (int r = 0; r < 4; ++r) pk[r] = (__bf16)acc[r];
            *(bf16x4*)&VT[((long)bh * 16 + d) * 512 + nloc] = pk;
        } else {
            __bf16* dst = t ? Kb : Qb;
#pragma unroll
            for (int r = 0; r < 4; ++r)
                dst[((long)bh * 512 + nloc + r) * 16 + d] = (__bf16)acc[r];
        }
    }
}

// ---------------------------------------------------------------------------
// attn: block = (16-row n-strip, b), 8 waves = 8 heads.
// adj strip (16x512 f32 = 32 KB) staged once in XOR-swizzled LDS, one barrier.
// Per 32-m tile: 2x QK mfma (zero-padded k) -> tanh -> PV as ONE permuted-K
// 16x16x32 mfma (k-slot (g,e) <-> m = g*4+e | 16+g*4+(e-4)); no P shuffle/LDS.
// ---------------------------------------------------------------------------
__device__ __forceinline__ float tanh_q(float sadj) {
    // tanh(sadj * 0.25) = 1 - 2 / (exp2(sadj * 0.5*log2(e)) + 1)
    const float C = 0.7213475204444817f;
    float e = __builtin_amdgcn_exp2f(sadj * C);
    return 1.0f - 2.0f * __builtin_amdgcn_rcpf(e + 1.0f);
}

__global__ __launch_bounds__(512) void attn_kernel(
    const float* __restrict__ adj,
    const __bf16* __restrict__ Qb, const __bf16* __restrict__ Kb,
    const __bf16* __restrict__ VT, __bf16* __restrict__ Hb)
{
    __shared__ __align__(16) float adjL[16][512];   // 32 KB, rows XOR-swizzled

    const int tid  = threadIdx.x;
    const int lane = tid & 63;
    const int h    = tid >> 6;        // wave = head
    const int g    = lane >> 4;
    const int lr   = lane & 15;
    const int b    = blockIdx.y;
    const int n0   = blockIdx.x * 16;
    const int bh   = b * 8 + h;

    // stage adj strip: global linear -> LDS with col ^= (row&7)<<4
    const char* strip = (const char*)(adj + ((long)b * 512 + n0) * 512);
    f32x4 tmp[4];
#pragma unroll
    for (int i = 0; i < 4; ++i)
        tmp[i] = *(const f32x4*)(strip + i * 8192 + tid * 16);
#pragma unroll
    for (int i = 0; i < 4; ++i) {
        int o = i * 8192 + tid * 16;
        int row = o >> 11, col = o & 2047;
        *(f32x4*)((char*)adjL + row * 2048 + (col ^ ((row & 7) << 4))) = tmp[i];
    }

    bf16x8 qf = {};   // B-operand: Q[n0+lr][d], d = g*8..+8 (g<2), zeros above
    if (g < 2) qf = *(const bf16x8*)&Qb[((long)bh * 512 + n0 + lr) * 16 + g * 8];

    const __bf16* Kbase = Kb + (long)bh * 512 * 16;
    const __bf16* Vrow  = VT + ((long)bh * 16 + lr) * 512;   // row d = lr
    const char*   aRow  = (const char*)adjL + lr * 2048;
    const int     sw    = (lr & 7) << 4;

    __syncthreads();

    f32x4 accH = {0.f, 0.f, 0.f, 0.f};
#pragma unroll 2
    for (int t = 0; t < 16; ++t) {
        const int m0 = t * 32;
        bf16x8 kf0 = {}, kf1 = {};    // A-operand: K[m][d], zeros for k>=16
        if (g < 2) {
            kf0 = *(const bf16x8*)&Kbase[(m0 + lr) * 16 + g * 8];
            kf1 = *(const bf16x8*)&Kbase[(m0 + 16 + lr) * 16 + g * 8];
        }
        bf16x4 v0 = *(const bf16x4*)&Vrow[m0 + g * 4];        // V[m=g*4..+4][lr]
        bf16x4 v1 = *(const bf16x4*)&Vrow[m0 + 16 + g * 4];
        f32x4 a0 = *(const f32x4*)(aRow + (((m0 + g * 4) * 4) ^ sw));
        f32x4 a1 = *(const f32x4*)(aRow + (((m0 + 16 + g * 4) * 4) ^ sw));

        const f32x4 z = {0.f, 0.f, 0.f, 0.f};
        // lane(g,lr) gets S[m = m0(+16) + g*4 + r][n = n0+lr]
        f32x4 s0 = MFMA16(kf0, qf, z);
        f32x4 s1 = MFMA16(kf1, qf, z);

        bf16x8 paf, vf;               // permuted-K PV operands
#pragma unroll
        for (int r = 0; r < 4; ++r) {
            paf[r]     = (__bf16)tanh_q(s0[r] * a0[r]);
            paf[4 + r] = (__bf16)tanh_q(s1[r] * a1[r]);
            vf[r]      = v0[r];
            vf[4 + r]  = v1[r];
        }
        accH = MFMA16(paf, vf, accH);   // D[n=n0+g*4+r][d=lr] accumulates
    }

#pragma unroll
    for (int r = 0; r < 4; ++r)
        Hb[((long)b * 512 + n0 + g * 4 + r) * 128 + h * 16 + lr] = (__bf16)accH[r];
}

// ---------------------------------------------------------------------------
// oproj: out = relu(Hb @ wo). 1024 blocks x 256 thr; block = 16 rows;
// wave w handles cols w*32..+32. B-frags direct from global WoTb.
// ---------------------------------------------------------------------------
__global__ __launch_bounds__(256) void oproj_kernel(
    const __bf16* __restrict__ Hb, const __bf16* __restrict__ WoTb,
    float* __restrict__ out)
{
    const int tid = threadIdx.x, lane = tid & 63, w = tid >> 6;
    const int g = lane >> 4, lr = lane & 15;
    const long R0 = (long)blockIdx.x * 16;

    bf16x8 af[4];
#pragma unroll
    for (int kk = 0; kk < 4; ++kk)
        af[kk] = *(const bf16x8*)&Hb[(R0 + lr) * 128 + kk * 32 + g * 8];

#pragma unroll
    for (int i = 0; i < 2; ++i) {
        const int j0 = w * 32 + i * 16;
        f32x4 acc = {0.f, 0.f, 0.f, 0.f};
#pragma unroll
        for (int kk = 0; kk < 4; ++kk) {
            bf16x8 bf = *(const bf16x8*)&WoTb[(j0 + lr) * 128 + kk * 32 + g * 8];
            acc = MFMA16(af[kk], bf, acc);
        }
#pragma unroll
        for (int r = 0; r < 4; ++r)
            out[(R0 + g * 4 + r) * 128 + j0 + lr] = fmaxf(acc[r], 0.f);
    }
}

// ---------------------------------------------------------------------------
extern "C" void kernel_launch(void* const* d_in, const int* in_sizes, int n_in,
                              void* d_out, int out_size, void* d_ws, size_t ws_size,
                              hipStream_t stream) {
    const float* x   = (const float*)d_in[0];
    const float* adj = (const float*)d_in[1];
    const float* wq  = (const float*)d_in[2];
    const float* wk  = (const float*)d_in[3];
    const float* wv  = (const float*)d_in[4];
    const float* wo  = (const float*)d_in[5];
    float* out = (float*)d_out;

    char* wsb = (char*)d_ws;
    __bf16* WTb  = (__bf16*)wsb;                    // 384*64  bf16 = 48 KiB
    __bf16* WoTb = (__bf16*)(wsb + 49152);          // 128*128 bf16 = 32 KiB
    __bf16* Qb   = (__bf16*)(wsb + 81920);          // 256*512*16 bf16 = 4 MiB
    __bf16* Kb   = Qb + 2097152;
    __bf16* VT   = Kb + 2097152;                    // [bh][16][512]
    __bf16* Hb   = VT + 2097152;                    // [B*N][128]

    prep_kernel<<<40, 256, 0, stream>>>(wq, wk, wv, wo, WTb, WoTb);
    qkv_kernel<<<1024, 256, 0, stream>>>(x, WTb, Qb, Kb, VT);
    attn_kernel<<<dim3(32, 32), 512, 0, stream>>>(adj, Qb, Kb, VT, Hb);
    oproj_kernel<<<1024, 256, 0, stream>>>(Hb, WoTb, out);
}

// Round 6
// 128.521 us; speedup vs baseline: 1.1972x; 1.1133x over previous
//
#include <hip/hip_runtime.h>

// ---------------------------------------------------------------------------
// GraphAttn: out = relu( (mergeheads( tanh((QK^T/4) * adj) @ V )) @ wo )
// B=32, N=512, F_IN=64, H=8, D=16, OUT=128.
// v3: attn restructured — QBLK=32 rows/block (halves K/V re-read, 2x arith
//     per load), hand ping-pong software pipeline (two Tile register sets),
//     launch_bounds(512,4) to force pipelining-friendly VGPR budget.
//     prep/qkv/oproj unchanged from v2.
// ---------------------------------------------------------------------------

typedef __bf16 bf16x8 __attribute__((ext_vector_type(8)));
typedef __bf16 bf16x4 __attribute__((ext_vector_type(4)));
typedef float  f32x4  __attribute__((ext_vector_type(4)));

#define MFMA16(a, b, c) __builtin_amdgcn_mfma_f32_16x16x32_bf16((a), (b), (c), 0, 0, 0)

// ---------------------------------------------------------------------------
// prep: WTb[j][k] = w{q,k,v}[k][j&127] (384x64), WoTb[j][k] = wo[k][j] (128x128)
// ---------------------------------------------------------------------------
__global__ __launch_bounds__(256) void prep_kernel(
    const float* __restrict__ wq, const float* __restrict__ wk,
    const float* __restrict__ wv, const float* __restrict__ wo,
    __bf16* __restrict__ WTb, __bf16* __restrict__ WoTb)
{
    int idx = blockIdx.x * 256 + threadIdx.x;
    if (idx < 6144) {                       // 96 j-groups x 64 k
        int j4 = idx % 96, k = idx / 96, j = j4 * 4;
        const float* w = (j < 128) ? wq : ((j < 256) ? wk : wv);
        f32x4 v = *(const f32x4*)&w[k * 128 + (j & 127)];
#pragma unroll
        for (int e = 0; e < 4; ++e) WTb[(j + e) * 64 + k] = (__bf16)v[e];
    } else if (idx < 6144 + 4096) {         // 32 j-groups x 128 k
        int i2 = idx - 6144;
        int j4 = i2 % 32, k = i2 / 32, j = j4 * 4;
        f32x4 v = *(const f32x4*)&wo[k * 128 + j];
#pragma unroll
        for (int e = 0; e < 4; ++e) WoTb[(j + e) * 128 + k] = (__bf16)v[e];
    }
}

// ---------------------------------------------------------------------------
// qkv: Q,K = [bh][n][16] row-major bf16; VT = [bh][16][n].
// ---------------------------------------------------------------------------
__global__ __launch_bounds__(256) void qkv_kernel(
    const float* __restrict__ x, const __bf16* __restrict__ WTb,
    __bf16* __restrict__ Qb, __bf16* __restrict__ Kb, __bf16* __restrict__ VT)
{
    const int tid = threadIdx.x, lane = tid & 63, w = tid >> 6;
    const int g = lane >> 4, lr = lane & 15;
    const long R0 = (long)blockIdx.x * 16;
    const int b = (int)(R0 >> 9);
    const int nloc = (int)(R0 & 511) + g * 4;

    bf16x8 af[2];
#pragma unroll
    for (int kk = 0; kk < 2; ++kk) {
        const float* xp = x + (R0 + lr) * 64 + kk * 32 + g * 8;
        f32x4 x0 = *(const f32x4*)xp, x1 = *(const f32x4*)(xp + 4);
        bf16x8 a;
#pragma unroll
        for (int e = 0; e < 4; ++e) { a[e] = (__bf16)x0[e]; a[4 + e] = (__bf16)x1[e]; }
        af[kk] = a;
    }

#pragma unroll 2
    for (int i = 0; i < 6; ++i) {
        const int j0 = (w * 6 + i) * 16;
        f32x4 acc = {0.f, 0.f, 0.f, 0.f};
#pragma unroll
        for (int kk = 0; kk < 2; ++kk) {
            bf16x8 bf = *(const bf16x8*)&WTb[(j0 + lr) * 64 + kk * 32 + g * 8];
            acc = MFMA16(af[kk], bf, acc);
        }
        const int jj = (j0 + lr) & 127, hh = jj >> 4, d = jj & 15;
        const int bh = b * 8 + hh, t = j0 >> 7;
        if (t == 2) {
            bf16x4 pk;
#pragma unroll
            for (int r = 0; r < 4; ++r) pk[r] = (__bf16)acc[r];
            *(bf16x4*)&VT[((long)bh * 16 + d) * 512 + nloc] = pk;
        } else {
            __bf16* dst = t ? Kb : Qb;
#pragma unroll
            for (int r = 0; r < 4; ++r)
                dst[((long)bh * 512 + nloc + r) * 16 + d] = (__bf16)acc[r];
        }
    }
}

// ---------------------------------------------------------------------------
// attn v3: block = (32-row n-strip, b), 8 waves = 8 heads.
// adj strip (32x512 f32 = 64 KB) staged once, XOR-swizzled rows, one barrier.
// m-loop: explicit 2-stage ping-pong (load tile t+1 before computing tile t).
// Per 32-m tile: 4 QK mfma (two n-subs), 16 tanh, 2 permuted-K PV mfma.
// ---------------------------------------------------------------------------
__device__ __forceinline__ float tanh_q(float sadj) {
    // tanh(sadj * 0.25) = 1 - 2 / (exp2(sadj * 0.5*log2(e)) + 1)
    const float C = 0.7213475204444817f;
    float e = __builtin_amdgcn_exp2f(sadj * C);
    return 1.0f - 2.0f * __builtin_amdgcn_rcpf(e + 1.0f);
}

struct Tile {
    bf16x8 kf0, kf1;
    bf16x4 v0, v1;
    f32x4 a00, a01, a10, a11;
};

__device__ __forceinline__ Tile load_tile(
    int m0, bool gactive, const __bf16* Kbase, int lr, int g,
    const __bf16* Vrow, const char* aRow0, const char* aRow1, int sw)
{
    Tile t;
    t.kf0 = {}; t.kf1 = {};
    if (gactive) {
        t.kf0 = *(const bf16x8*)&Kbase[(m0 + lr) * 16 + g * 8];
        t.kf1 = *(const bf16x8*)&Kbase[(m0 + 16 + lr) * 16 + g * 8];
    }
    t.v0 = *(const bf16x4*)&Vrow[m0 + g * 4];
    t.v1 = *(const bf16x4*)&Vrow[m0 + 16 + g * 4];
    const int c0 = ((m0 + g * 4) * 4) ^ sw;
    const int c1 = ((m0 + 16 + g * 4) * 4) ^ sw;
    t.a00 = *(const f32x4*)(aRow0 + c0);
    t.a01 = *(const f32x4*)(aRow0 + c1);
    t.a10 = *(const f32x4*)(aRow1 + c0);
    t.a11 = *(const f32x4*)(aRow1 + c1);
    return t;
}

__device__ __forceinline__ void compute_tile(
    const Tile& t, bf16x8 qf0, bf16x8 qf1, f32x4& acc0, f32x4& acc1)
{
    const f32x4 z = {0.f, 0.f, 0.f, 0.f};
    // lane(g,lr): s[r] = S[m = m0(+16) + g*4 + r][n-sub row lr]
    f32x4 s00 = MFMA16(t.kf0, qf0, z);
    f32x4 s01 = MFMA16(t.kf1, qf0, z);
    f32x4 s10 = MFMA16(t.kf0, qf1, z);
    f32x4 s11 = MFMA16(t.kf1, qf1, z);
    bf16x8 p0, p1, vf;
#pragma unroll
    for (int r = 0; r < 4; ++r) {
        p0[r]     = (__bf16)tanh_q(s00[r] * t.a00[r]);
        p0[4 + r] = (__bf16)tanh_q(s01[r] * t.a01[r]);
        p1[r]     = (__bf16)tanh_q(s10[r] * t.a10[r]);
        p1[4 + r] = (__bf16)tanh_q(s11[r] * t.a11[r]);
        vf[r]     = t.v0[r];
        vf[4 + r] = t.v1[r];
    }
    acc0 = MFMA16(p0, vf, acc0);   // h[n-sub0 = n0+g*4+r][d=lr]
    acc1 = MFMA16(p1, vf, acc1);   // h[n-sub1 = n0+16+g*4+r][d=lr]
}

__global__ __launch_bounds__(512, 4) void attn_kernel(
    const float* __restrict__ adj,
    const __bf16* __restrict__ Qb, const __bf16* __restrict__ Kb,
    const __bf16* __restrict__ VT, __bf16* __restrict__ Hb)
{
    __shared__ __align__(16) float adjL[32][512];   // 64 KB, rows XOR-swizzled

    const int tid  = threadIdx.x;
    const int lane = tid & 63;
    const int h    = tid >> 6;        // wave = head
    const int g    = lane >> 4;
    const int lr   = lane & 15;
    const int b    = blockIdx.y;
    const int n0   = blockIdx.x * 32;
    const int bh   = b * 8 + h;

    // stage adj strip (32 rows x 512): 8 x 8KB rounds, swizzle col^=(row&7)<<4
    const char* strip = (const char*)(adj + ((long)b * 512 + n0) * 512);
    f32x4 tmp[8];
#pragma unroll
    for (int i = 0; i < 8; ++i)
        tmp[i] = *(const f32x4*)(strip + i * 8192 + tid * 16);
#pragma unroll
    for (int i = 0; i < 8; ++i) {
        int o = i * 8192 + tid * 16;
        int row = o >> 11, col = o & 2047;
        *(f32x4*)((char*)adjL + row * 2048 + (col ^ ((row & 7) << 4))) = tmp[i];
    }

    const bool ga = (g < 2);
    bf16x8 qf0 = {}, qf1 = {};   // B-operand: Q[n][d], zeros for k>=16
    if (ga) {
        qf0 = *(const bf16x8*)&Qb[((long)bh * 512 + n0 + lr) * 16 + g * 8];
        qf1 = *(const bf16x8*)&Qb[((long)bh * 512 + n0 + 16 + lr) * 16 + g * 8];
    }

    const __bf16* Kbase = Kb + (long)bh * 512 * 16;
    const __bf16* Vrow  = VT + ((long)bh * 16 + lr) * 512;      // row d = lr
    const char*   aRow0 = (const char*)adjL + lr * 2048;        // n = n0+lr
    const char*   aRow1 = (const char*)adjL + (16 + lr) * 2048; // n = n0+16+lr
    const int     sw    = (lr & 7) << 4;   // (16+lr)&7 == lr&7: same swizzle

    __syncthreads();

    f32x4 acc0 = {0.f, 0.f, 0.f, 0.f}, acc1 = {0.f, 0.f, 0.f, 0.f};

    // explicit 2-deep ping-pong over 16 tiles of 32 m
    Tile tA = load_tile(0, ga, Kbase, lr, g, Vrow, aRow0, aRow1, sw);
#pragma unroll 1
    for (int t = 0; t < 16; t += 2) {
        Tile tB = load_tile((t + 1) * 32, ga, Kbase, lr, g, Vrow, aRow0, aRow1, sw);
        compute_tile(tA, qf0, qf1, acc0, acc1);
        if (t + 2 < 16)
            tA = load_tile((t + 2) * 32, ga, Kbase, lr, g, Vrow, aRow0, aRow1, sw);
        compute_tile(tB, qf0, qf1, acc0, acc1);
    }

#pragma unroll
    for (int r = 0; r < 4; ++r) {
        Hb[((long)b * 512 + n0 + g * 4 + r) * 128 + h * 16 + lr]      = (__bf16)acc0[r];
        Hb[((long)b * 512 + n0 + 16 + g * 4 + r) * 128 + h * 16 + lr] = (__bf16)acc1[r];
    }
}

// ---------------------------------------------------------------------------
// oproj: out = relu(Hb @ wo).
// ---------------------------------------------------------------------------
__global__ __launch_bounds__(256) void oproj_kernel(
    const __bf16* __restrict__ Hb, const __bf16* __restrict__ WoTb,
    float* __restrict__ out)
{
    const int tid = threadIdx.x, lane = tid & 63, w = tid >> 6;
    const int g = lane >> 4, lr = lane & 15;
    const long R0 = (long)blockIdx.x * 16;

    bf16x8 af[4];
#pragma unroll
    for (int kk = 0; kk < 4; ++kk)
        af[kk] = *(const bf16x8*)&Hb[(R0 + lr) * 128 + kk * 32 + g * 8];

#pragma unroll
    for (int i = 0; i < 2; ++i) {
        const int j0 = w * 32 + i * 16;
        f32x4 acc = {0.f, 0.f, 0.f, 0.f};
#pragma unroll
        for (int kk = 0; kk < 4; ++kk) {
            bf16x8 bf = *(const bf16x8*)&WoTb[(j0 + lr) * 128 + kk * 32 + g * 8];
            acc = MFMA16(af[kk], bf, acc);
        }
#pragma unroll
        for (int r = 0; r < 4; ++r)
            out[(R0 + g * 4 + r) * 128 + j0 + lr] = fmaxf(acc[r], 0.f);
    }
}

// ---------------------------------------------------------------------------
extern "C" void kernel_launch(void* const* d_in, const int* in_sizes, int n_in,
                              void* d_out, int out_size, void* d_ws, size_t ws_size,
                              hipStream_t stream) {
    const float* x   = (const float*)d_in[0];
    const float* adj = (const float*)d_in[1];
    const float* wq  = (const float*)d_in[2];
    const float* wk  = (const float*)d_in[3];
    const float* wv  = (const float*)d_in[4];
    const float* wo  = (const float*)d_in[5];
    float* out = (float*)d_out;

    char* wsb = (char*)d_ws;
    __bf16* WTb  = (__bf16*)wsb;                    // 384*64  bf16 = 48 KiB
    __bf16* WoTb = (__bf16*)(wsb + 49152);          // 128*128 bf16 = 32 KiB
    __bf16* Qb   = (__bf16*)(wsb + 81920);          // 256*512*16 bf16 = 4 MiB
    __bf16* Kb   = Qb + 2097152;
    __bf16* VT   = Kb + 2097152;                    // [bh][16][512]
    __bf16* Hb   = VT + 2097152;                    // [B*N][128]

    prep_kernel<<<40, 256, 0, stream>>>(wq, wk, wv, wo, WTb, WoTb);
    qkv_kernel<<<1024, 256, 0, stream>>>(x, WTb, Qb, Kb, VT);
    attn_kernel<<<dim3(16, 32), 512, 0, stream>>>(adj, Qb, Kb, VT, Hb);
    oproj_kernel<<<1024, 256, 0, stream>>>(Hb, WoTb, out);
}

// Round 7
// 124.316 us; speedup vs baseline: 1.2376x; 1.0338x over previous
//
#include <hip/hip_runtime.h>

// ---------------------------------------------------------------------------
// GraphAttn: out = relu( (mergeheads( tanh((QK^T/4) * adj) @ V )) @ wo )
// B=32, N=512, F_IN=64, H=8, D=16, OUT=128.
// v4: attn+oproj fused. XCD-bijective swizzle pins each batch's 16 strips to
//     one XCD (K/V L2-resident); adj staged nontemporal -> bf16 LDS,
//     pre-scaled by tanh const; h -> LDS (reusing adj buffer) -> oproj MFMA.
//     prep/qkv unchanged.
// ---------------------------------------------------------------------------

typedef __bf16 bf16x8 __attribute__((ext_vector_type(8)));
typedef __bf16 bf16x4 __attribute__((ext_vector_type(4)));
typedef float  f32x4  __attribute__((ext_vector_type(4)));

#define MFMA16(a, b, c) __builtin_amdgcn_mfma_f32_16x16x32_bf16((a), (b), (c), 0, 0, 0)

// ---------------------------------------------------------------------------
// prep: WTb[j][k] = w{q,k,v}[k][j&127] (384x64), WoTb[j][k] = wo[k][j] (128x128)
// ---------------------------------------------------------------------------
__global__ __launch_bounds__(256) void prep_kernel(
    const float* __restrict__ wq, const float* __restrict__ wk,
    const float* __restrict__ wv, const float* __restrict__ wo,
    __bf16* __restrict__ WTb, __bf16* __restrict__ WoTb)
{
    int idx = blockIdx.x * 256 + threadIdx.x;
    if (idx < 6144) {                       // 96 j-groups x 64 k
        int j4 = idx % 96, k = idx / 96, j = j4 * 4;
        const float* w = (j < 128) ? wq : ((j < 256) ? wk : wv);
        f32x4 v = *(const f32x4*)&w[k * 128 + (j & 127)];
#pragma unroll
        for (int e = 0; e < 4; ++e) WTb[(j + e) * 64 + k] = (__bf16)v[e];
    } else if (idx < 6144 + 4096) {         // 32 j-groups x 128 k
        int i2 = idx - 6144;
        int j4 = i2 % 32, k = i2 / 32, j = j4 * 4;
        f32x4 v = *(const f32x4*)&wo[k * 128 + j];
#pragma unroll
        for (int e = 0; e < 4; ++e) WoTb[(j + e) * 128 + k] = (__bf16)v[e];
    }
}

// ---------------------------------------------------------------------------
// qkv: Q,K = [bh][n][16] row-major bf16; VT = [bh][16][n].
// ---------------------------------------------------------------------------
__global__ __launch_bounds__(256) void qkv_kernel(
    const float* __restrict__ x, const __bf16* __restrict__ WTb,
    __bf16* __restrict__ Qb, __bf16* __restrict__ Kb, __bf16* __restrict__ VT)
{
    const int tid = threadIdx.x, lane = tid & 63, w = tid >> 6;
    const int g = lane >> 4, lr = lane & 15;
    const long R0 = (long)blockIdx.x * 16;
    const int b = (int)(R0 >> 9);
    const int nloc = (int)(R0 & 511) + g * 4;

    bf16x8 af[2];
#pragma unroll
    for (int kk = 0; kk < 2; ++kk) {
        const float* xp = x + (R0 + lr) * 64 + kk * 32 + g * 8;
        f32x4 x0 = *(const f32x4*)xp, x1 = *(const f32x4*)(xp + 4);
        bf16x8 a;
#pragma unroll
        for (int e = 0; e < 4; ++e) { a[e] = (__bf16)x0[e]; a[4 + e] = (__bf16)x1[e]; }
        af[kk] = a;
    }

#pragma unroll 2
    for (int i = 0; i < 6; ++i) {
        const int j0 = (w * 6 + i) * 16;
        f32x4 acc = {0.f, 0.f, 0.f, 0.f};
#pragma unroll
        for (int kk = 0; kk < 2; ++kk) {
            bf16x8 bf = *(const bf16x8*)&WTb[(j0 + lr) * 64 + kk * 32 + g * 8];
            acc = MFMA16(af[kk], bf, acc);
        }
        const int jj = (j0 + lr) & 127, hh = jj >> 4, d = jj & 15;
        const int bh = b * 8 + hh, t = j0 >> 7;
        if (t == 2) {
            bf16x4 pk;
#pragma unroll
            for (int r = 0; r < 4; ++r) pk[r] = (__bf16)acc[r];
            *(bf16x4*)&VT[((long)bh * 16 + d) * 512 + nloc] = pk;
        } else {
            __bf16* dst = t ? Kb : Qb;
#pragma unroll
            for (int r = 0; r < 4; ++r)
                dst[((long)bh * 512 + nloc + r) * 16 + d] = (__bf16)acc[r];
        }
    }
}

// ---------------------------------------------------------------------------
// attn+oproj fused.  Block = (b, 32-row n-strip), 8 waves = 8 heads.
// XCD-bijective: linear block l -> (b, strip) with l % 8 == b % 8, so each
// batch's K/V/Q (384 KB) stays resident in one XCD's 4 MB L2.
// adjL: bf16[32][520] pre-scaled by C (nontemporal f32 loads, padded rows).
// m-loop: 2-deep ping-pong on K/V; adj read from LDS inside compute.
// Tail: h -> hL f32[32][132] (reuses adjL space) -> 16x16x32 oproj -> relu.
// ---------------------------------------------------------------------------
__device__ __forceinline__ float tanh_e(float x) {
    // x = s * (adj*C), C = 0.25*2*log2(e);  tanh(s*adj/4) = 1 - 2/(2^x + 1)
    float e = __builtin_amdgcn_exp2f(x);
    return 1.0f - 2.0f * __builtin_amdgcn_rcpf(e + 1.0f);
}

struct Tile {
    bf16x8 kf0, kf1;
    bf16x4 v0, v1;
};

__device__ __forceinline__ Tile load_tile(
    int m0, bool ga, const __bf16* Kbase, int lr, int g, const __bf16* Vrow)
{
    Tile t;
    t.kf0 = {}; t.kf1 = {};
    if (ga) {
        t.kf0 = *(const bf16x8*)&Kbase[(m0 + lr) * 16 + g * 8];
        t.kf1 = *(const bf16x8*)&Kbase[(m0 + 16 + lr) * 16 + g * 8];
    }
    t.v0 = *(const bf16x4*)&Vrow[m0 + g * 4];
    t.v1 = *(const bf16x4*)&Vrow[m0 + 16 + g * 4];
    return t;
}

__device__ __forceinline__ void compute_tile(
    const Tile& t, int m0, bf16x8 qf0, bf16x8 qf1,
    const __bf16* aR0, const __bf16* aR1, int g,
    f32x4& acc0, f32x4& acc1)
{
    // adj (bf16, pre-scaled) from LDS; issue before MFMAs so latency overlaps
    bf16x4 ba00 = *(const bf16x4*)&aR0[m0 + g * 4];
    bf16x4 ba01 = *(const bf16x4*)&aR0[m0 + 16 + g * 4];
    bf16x4 ba10 = *(const bf16x4*)&aR1[m0 + g * 4];
    bf16x4 ba11 = *(const bf16x4*)&aR1[m0 + 16 + g * 4];

    const f32x4 z = {0.f, 0.f, 0.f, 0.f};
    // lane(g,lr): s[r] = S[m = m0(+16) + g*4 + r][n-sub row lr]
    f32x4 s00 = MFMA16(t.kf0, qf0, z);
    f32x4 s01 = MFMA16(t.kf1, qf0, z);
    f32x4 s10 = MFMA16(t.kf0, qf1, z);
    f32x4 s11 = MFMA16(t.kf1, qf1, z);

    bf16x8 p0, p1, vf;
#pragma unroll
    for (int r = 0; r < 4; ++r) {
        p0[r]     = (__bf16)tanh_e(s00[r] * (float)ba00[r]);
        p0[4 + r] = (__bf16)tanh_e(s01[r] * (float)ba01[r]);
        p1[r]     = (__bf16)tanh_e(s10[r] * (float)ba10[r]);
        p1[4 + r] = (__bf16)tanh_e(s11[r] * (float)ba11[r]);
        vf[r]     = t.v0[r];
        vf[4 + r] = t.v1[r];
    }
    acc0 = MFMA16(p0, vf, acc0);   // h[n-sub0 = n0+g*4+r][d=lr]
    acc1 = MFMA16(p1, vf, acc1);   // h[n-sub1 = n0+16+g*4+r][d=lr]
}

__global__ __launch_bounds__(512, 4) void attn_kernel(
    const float* __restrict__ adj,
    const __bf16* __restrict__ Qb, const __bf16* __restrict__ Kb,
    const __bf16* __restrict__ VT, const __bf16* __restrict__ WoTb,
    float* __restrict__ out)
{
    __shared__ __align__(16) char smem[33280];   // adjL bf16[32][520] | hL f32[32][132]

    const int tid  = threadIdx.x;
    const int lane = tid & 63;
    const int h    = tid >> 6;        // wave = head
    const int g    = lane >> 4;
    const int lr   = lane & 15;

    // XCD-bijective decode: l = ((b>>3)*16 + strip)*8 + (b&7)
    const int l  = blockIdx.x;
    const int q  = l >> 3;
    const int b  = (q >> 4) * 8 + (l & 7);
    const int n0 = (q & 15) * 32;
    const int bh = b * 8 + h;

    // ---- stage adj strip (32x512 f32 -> bf16*C), nontemporal, padded rows --
    const float C = 0.7213475204444817f;   // 0.25 * 2 * log2(e)
    __bf16* adjL = (__bf16*)smem;
    const float* strip = adj + ((long)b * 512 + n0) * 512;
#pragma unroll
    for (int i = 0; i < 8; ++i) {
        int o = i * 2048 + tid * 4;          // f32 index, row-major 512
        f32x4 v = __builtin_nontemporal_load((const f32x4*)(strip + o));
        int row = o >> 9, col = o & 511;
        bf16x4 w;
#pragma unroll
        for (int e = 0; e < 4; ++e) w[e] = (__bf16)(v[e] * C);
        *(bf16x4*)&adjL[row * 520 + col] = w;
    }

    const bool ga = (g < 2);
    bf16x8 qf0 = {}, qf1 = {};   // B-operand: Q[n][d], zeros for k>=16
    if (ga) {
        qf0 = *(const bf16x8*)&Qb[((long)bh * 512 + n0 + lr) * 16 + g * 8];
        qf1 = *(const bf16x8*)&Qb[((long)bh * 512 + n0 + 16 + lr) * 16 + g * 8];
    }
    const __bf16* Kbase = Kb + (long)bh * 512 * 16;
    const __bf16* Vrow  = VT + ((long)bh * 16 + lr) * 512;   // row d = lr
    const __bf16* aR0   = adjL + lr * 520;                   // n = n0+lr
    const __bf16* aR1   = adjL + (16 + lr) * 520;            // n = n0+16+lr

    __syncthreads();

    f32x4 acc0 = {0.f, 0.f, 0.f, 0.f}, acc1 = {0.f, 0.f, 0.f, 0.f};

    // 2-deep ping-pong over 16 tiles of 32 m
    Tile tA = load_tile(0, ga, Kbase, lr, g, Vrow);
#pragma unroll 1
    for (int t = 0; t < 16; t += 2) {
        Tile tB = load_tile((t + 1) * 32, ga, Kbase, lr, g, Vrow);
        compute_tile(tA, t * 32, qf0, qf1, aR0, aR1, g, acc0, acc1);
        if (t + 2 < 16)
            tA = load_tile((t + 2) * 32, ga, Kbase, lr, g, Vrow);
        compute_tile(tB, (t + 1) * 32, qf0, qf1, aR0, aR1, g, acc0, acc1);
    }

    // ---- fused oproj: h -> LDS (reuse adj buffer) -> MFMA with wo -> relu --
    __syncthreads();                       // all waves done reading adjL
    float* hL = (float*)smem;              // [32][132] f32
#pragma unroll
    for (int r = 0; r < 4; ++r) {
        hL[(g * 4 + r) * 132 + h * 16 + lr]        = acc0[r];
        hL[(16 + g * 4 + r) * 132 + h * 16 + lr]   = acc1[r];
    }
    __syncthreads();

    // A-frags: h[t*16+lr][kt*32+g*8..+8); B-frags: wo^T[j=h*16+lr][same k]
    f32x4 o0 = {0.f, 0.f, 0.f, 0.f}, o1 = {0.f, 0.f, 0.f, 0.f};
#pragma unroll
    for (int kt = 0; kt < 4; ++kt) {
        bf16x8 wf = *(const bf16x8*)&WoTb[(h * 16 + lr) * 128 + kt * 32 + g * 8];
        const float* hp0 = &hL[lr * 132 + kt * 32 + g * 8];
        const float* hp1 = &hL[(16 + lr) * 132 + kt * 32 + g * 8];
        f32x4 ha = *(const f32x4*)hp0, hb = *(const f32x4*)(hp0 + 4);
        f32x4 hc = *(const f32x4*)hp1, hd = *(const f32x4*)(hp1 + 4);
        bf16x8 a0, a1;
#pragma unroll
        for (int e = 0; e < 4; ++e) {
            a0[e] = (__bf16)ha[e]; a0[4 + e] = (__bf16)hb[e];
            a1[e] = (__bf16)hc[e]; a1[4 + e] = (__bf16)hd[e];
        }
        o0 = MFMA16(a0, wf, o0);
        o1 = MFMA16(a1, wf, o1);
    }

    const long obase = (long)b * 512 + n0;
#pragma unroll
    for (int r = 0; r < 4; ++r) {
        out[(obase + g * 4 + r) * 128 + h * 16 + lr]      = fmaxf(o0[r], 0.f);
        out[(obase + 16 + g * 4 + r) * 128 + h * 16 + lr] = fmaxf(o1[r], 0.f);
    }
}

// ---------------------------------------------------------------------------
extern "C" void kernel_launch(void* const* d_in, const int* in_sizes, int n_in,
                              void* d_out, int out_size, void* d_ws, size_t ws_size,
                              hipStream_t stream) {
    const float* x   = (const float*)d_in[0];
    const float* adj = (const float*)d_in[1];
    const float* wq  = (const float*)d_in[2];
    const float* wk  = (const float*)d_in[3];
    const float* wv  = (const float*)d_in[4];
    const float* wo  = (const float*)d_in[5];
    float* out = (float*)d_out;

    char* wsb = (char*)d_ws;
    __bf16* WTb  = (__bf16*)wsb;                    // 384*64  bf16 = 48 KiB
    __bf16* WoTb = (__bf16*)(wsb + 49152);          // 128*128 bf16 = 32 KiB
    __bf16* Qb   = (__bf16*)(wsb + 81920);          // 256*512*16 bf16 = 4 MiB
    __bf16* Kb   = Qb + 2097152;
    __bf16* VT   = Kb + 2097152;                    // [bh][16][512]

    prep_kernel<<<40, 256, 0, stream>>>(wq, wk, wv, wo, WTb, WoTb);
    qkv_kernel<<<1024, 256, 0, stream>>>(x, WTb, Qb, Kb, VT);
    attn_kernel<<<512, 512, 0, stream>>>(adj, Qb, Kb, VT, WoTb, out);
}